// Round 10
// baseline (289.734 us; speedup 1.0000x reference)
//
#include <hip/hip_runtime.h>
#include <math.h>

#define NH 32
#define NHK 8
#define HD 64
#define DMODEL 2048
#define LSEQ 2048
#define NB 2
#define QKV_N 3072   // 2048 q + 512 k + 512 v

typedef __attribute__((ext_vector_type(8))) short short8;
typedef __attribute__((ext_vector_type(4))) float floatx4;

__device__ __forceinline__ unsigned short f2bf(float f) {
  unsigned u = __float_as_uint(f);
  return (unsigned short)((u + 0x7FFFu + ((u >> 16) & 1u)) >> 16);  // RNE
}
__device__ __forceinline__ float bf2f(unsigned short v) {
  return __uint_as_float((unsigned)v << 16);
}
__device__ __forceinline__ float fast_exp2(float x) {
#if __has_builtin(__builtin_amdgcn_exp2f)
  return __builtin_amdgcn_exp2f(x);
#else
  return __expf(x * 0.69314718f);
#endif
}
// pack bf16(hi),bf16(lo) from two fp32 by truncation: 1 v_perm_b32
__device__ __forceinline__ unsigned pack_bf_trunc(float hi, float lo) {
  return __builtin_amdgcn_perm(__float_as_uint(hi), __float_as_uint(lo), 0x07060302u);
}
// async 16B global->LDS, per-lane global address; lds base must be
// wave-uniform, lanes land at base+lane*16
__device__ __forceinline__ void stage16g(const char* g_lane,
                                         unsigned short* lds_wave_base, int lane) {
#if __has_builtin(__builtin_amdgcn_global_load_lds)
  __builtin_amdgcn_global_load_lds(
      (const __attribute__((address_space(1))) void*)(g_lane),
      (__attribute__((address_space(3))) void*)(lds_wave_base), 16, 0, 0);
#else
  *(uint4*)(lds_wave_base + lane * 8) = *(const uint4*)g_lane;
#endif
}

// ---------------------------------------------------------------------------
// prep: fused {rope_tab | x->bf16 | Wq|Wk|Wv->bf16}.  All segment boundaries
// are 256-block-aligned -> no intra-block divergence.
// ---------------------------------------------------------------------------
__global__ __launch_bounds__(256) void prep(const float* __restrict__ x,
                                            const float* __restrict__ Wq,
                                            const float* __restrict__ Wk,
                                            const float* __restrict__ Wv,
                                            float2* __restrict__ tab,
                                            unsigned short* __restrict__ xb,
                                            unsigned short* __restrict__ wqkvb) {
  const int NTAB = LSEQ * 32;                    // 65536
  const int NX = NB * LSEQ * DMODEL / 4;         // 2097152
  int idx = blockIdx.x * 256 + threadIdx.x;
  if (idx < NTAB) {
    int d = idx & 31, l = idx >> 5;
    float invf = (float)pow(10000.0, -(double)d / 32.0);
    float ang = (float)l * invf;
    double sd, cd;
    sincos((double)ang, &sd, &cd);
    tab[idx] = make_float2((float)cd, (float)sd);
    return;
  }
  idx -= NTAB;
  if (idx < NX) {
    float4 v = ((const float4*)x)[idx];
    ushort4 o;
    o.x = f2bf(v.x); o.y = f2bf(v.y); o.z = f2bf(v.z); o.w = f2bf(v.w);
    ((ushort4*)xb)[idx] = o;
    return;
  }
  idx -= NX;
  const int NQ = DMODEL * DMODEL / 4, NK = 512 * DMODEL / 4;
  const float* src;
  int off;
  if (idx < NQ) { src = Wq; off = idx; }
  else if (idx < NQ + NK) { src = Wk; off = idx - NQ; }
  else { src = Wv; off = idx - NQ - NK; }
  float4 v = ((const float4*)src)[off];
  ushort4 o;
  o.x = f2bf(v.x); o.y = f2bf(v.y); o.z = f2bf(v.z); o.w = f2bf(v.w);
  ((ushort4*)wqkvb)[idx] = o;
}

// ---------------------------------------------------------------------------
// gemm8w (r10): bf16 NT GEMM, 128x128 tile, BK=32, EIGHT waves (2Mx4N, wave
// tile 64x32), 3 LDS K-tile slots (48 KB -> 3 blocks/CU = 24 waves/CU =
// 6 waves/SIMD), 2-tiles-ahead async staging with COUNTED vmcnt (steady
// vmcnt(2), 0 only on the last tile), one raw s_barrier per K-tile, setprio
// around MFMA clusters, T1 XCD swizzle, unroll-by-3 static slots.
//
// r9 post-mortem: nothing saturated (LDS ~60%, MFMA 32%, VALU 15%, HBM 17%)
// -> per-tile LATENCY floor.  Per-unit tile time: 347 ns @3blk/4w, 522 @2blk
// /4w, ~273 @1blk/8w (r5) -> waves-per-SIMD is the lever, and r6 showed
// cross-block waves (uncorrelated barrier phases) hide latency poorly.
// 8 waves/block puts 2 same-block waves on each SIMD between the SAME
// barriers: one wave's ds_read latency hides under its sibling's MFMA issue.
// Staging becomes exactly 2 loads/wave/tile (1 A + 1 B group of 16 rows);
// the staged LDS image is bit-identical to r6-r9 (group index = wave).
//
// Race-free invariants (per wave, unchanged):
//  - tile t lives in slot t%3; all reads in iter t touch only slot t%3
//  - stage issued in iter t targets slot (t+2)%3 = old tile t-1, consumed
//    into VGPRs before that wave reached the top-of-t barrier
//  - vmcnt(2) at top of iter t completes the oldest 2 loads = tile t's own
//    A+B; every wave does likewise before the barrier -> cross-wave complete
// ---------------------------------------------------------------------------
template <bool BF16C>
__global__ __launch_bounds__(512, 6) void gemm8w(const unsigned short* __restrict__ A,
                                                 const unsigned short* __restrict__ B,
                                                 void* __restrict__ Cv, int K, int ldc) {
  __shared__ unsigned short As[3 * 128 * 32];  // 24 KB
  __shared__ unsigned short Bs[3 * 128 * 32];  // 24 KB

  const int tid = threadIdx.x;
  const int wave = tid >> 6, lane = tid & 63;   // wave 0..7
  const int quad = lane >> 4, l16 = lane & 15;
  const int wm = wave & 1, wn = wave >> 1;      // 2 x 4 wave grid

  // --- XCD-chunked bijective block swizzle (nwg % 8 == 0: 768 and 512)
  const int nwg = gridDim.x * gridDim.y;
  const int orig = blockIdx.y * gridDim.x + blockIdx.x;
  const int swz = (orig & 7) * (nwg >> 3) + (orig >> 3);
  const int bx = swz % gridDim.x, by = swz / gridDim.x;
  const int m0 = by * 128, n0 = bx * 128;

  const int kt = K >> 5;  // number of BK=32 K-tiles

  // staging source (per-lane): wave stages 16-row group `wave` of A and B;
  // row = wave*16 + lane>>2, chunk = (lane&3)^((lane>>3)&3) (pre-swizzled
  // for the sw8 read; key (row mod 16)>>1 matches read side)
  const int sgrow = wave * 16 + (lane >> 2);
  const int cchunk = (lane & 3) ^ ((lane >> 3) & 3);
  const char* AgB = (const char*)(A + (size_t)(m0 + sgrow) * K + cchunk * 8);
  const char* BgB = (const char*)(B + (size_t)(n0 + sgrow) * K + cchunk * 8);

  auto stageA = [&](int slot, int t2) {
    stage16g(AgB + (size_t)t2 * 64, &As[slot * 4096 + wave * 512], lane);
  };
  auto stageB = [&](int slot, int t2) {
    stage16g(BgB + (size_t)t2 * 64, &Bs[slot * 4096 + wave * 512], lane);
  };

  // read swizzle: chunk quad of row r sits at position quad^((r>>1)&3)
  const int sw8 = (quad ^ ((l16 >> 1) & 3)) * 8;

  floatx4 acc[4][2] = {};

  // prologue: stage tiles 0,1 (2 loads/wave each -> 4 outstanding)
  stageA(0, 0); stageB(0, 0);
  stageA(1, 1); stageB(1, 1);

  // tile body; sl/sl2 become compile-time constants in the unrolled groups
  auto tile = [&](int t, int sl, int sl2) {
    if (t + 1 < kt) asm volatile("s_waitcnt vmcnt(2)" ::: "memory");
    else            asm volatile("s_waitcnt vmcnt(0)" ::: "memory");
    __builtin_amdgcn_s_barrier();
    __builtin_amdgcn_sched_barrier(0);

    const unsigned short* Arow = &As[sl * 4096] + (wm * 64 + l16) * 32 + sw8;
    const unsigned short* Brow = &Bs[sl * 4096] + (wn * 32 + l16) * 32 + sw8;

    short8 bfr[2], af[4];
#pragma unroll
    for (int j = 0; j < 2; ++j) bfr[j] = *(const short8*)(Brow + j * 16 * 32);
#pragma unroll
    for (int i = 0; i < 4; ++i) af[i] = *(const short8*)(Arow + i * 16 * 32);

    if (t + 2 < kt) stageA(sl2, t + 2);

    __builtin_amdgcn_s_setprio(1);
#pragma unroll
    for (int i = 0; i < 2; ++i)
#pragma unroll
      for (int j = 0; j < 2; ++j)
        acc[i][j] = __builtin_amdgcn_mfma_f32_16x16x32_bf16(af[i], bfr[j], acc[i][j], 0, 0, 0);
    __builtin_amdgcn_s_setprio(0);

    if (t + 2 < kt) stageB(sl2, t + 2);

    __builtin_amdgcn_s_setprio(1);
#pragma unroll
    for (int i = 2; i < 4; ++i)
#pragma unroll
      for (int j = 0; j < 2; ++j)
        acc[i][j] = __builtin_amdgcn_mfma_f32_16x16x32_bf16(af[i], bfr[j], acc[i][j], 0, 0, 0);
    __builtin_amdgcn_s_setprio(0);
  };

#pragma unroll 1
  for (int g = 0; g < kt / 3; ++g) {
#pragma unroll
    for (int u3 = 0; u3 < 3; ++u3)
      tile(g * 3 + u3, u3, (u3 + 2) % 3);   // static slots after unroll
  }
#pragma unroll 1
  for (int t = (kt / 3) * 3; t < kt; ++t)
    tile(t, t % 3, (t + 2) % 3);            // <=2 tail tiles, runtime slot

#pragma unroll
  for (int i = 0; i < 4; ++i)
#pragma unroll
    for (int j = 0; j < 2; ++j)
#pragma unroll
      for (int r = 0; r < 4; ++r) {
        size_t idx = (size_t)(m0 + wm * 64 + i * 16 + quad * 4 + r) * ldc +
                     n0 + wn * 32 + j * 16 + l16;
        if (BF16C)
          ((unsigned short*)Cv)[idx] = f2bf(acc[i][j][r]);
        else
          ((float*)Cv)[idx] = acc[i][j][r];
      }
}

// ---------------------------------------------------------------------------
// mid: fused {RoPE-k | V-transpose | Wo->bf16}, all consumers of post-gemm1
// state.  Block-aligned segments:
//   blocks [0,4096):    ropek  (1,048,576 threads)
//   blocks [4096,4608): vt     (512 shaped blocks, uses LDS+syncthreads)
//   blocks [4608,8704): cvt Wo (1,048,576 threads; wqkvb dead -> wob reuse ok)
// ---------------------------------------------------------------------------
__global__ __launch_bounds__(256) void mid(const unsigned short* __restrict__ qkvb,
                                           const float2* __restrict__ tab,
                                           const float* __restrict__ Wo,
                                           unsigned short* __restrict__ kb,
                                           unsigned short* __restrict__ vtb,
                                           unsigned short* __restrict__ wob) {
  __shared__ unsigned short Lt[64][72];
  const int bid = blockIdx.x, tid = threadIdx.x;
  if (bid < 4096) {
    // ---- RoPE k -> kb [B, HK, L, 64]
    int t = bid * 256 + tid;
    int d = t & 31;
    int rest = t >> 5;
    int khead = rest & 7;
    int bl = rest >> 3;
    int l = bl & (LSEQ - 1);
    int b = bl >> 11;
    const unsigned short* src = qkvb + (size_t)bl * QKV_N + DMODEL + khead * HD;
    float2 cs = tab[(size_t)l * 32 + d];
    float x1 = bf2f(src[d]), x2 = bf2f(src[d + 32]);
    unsigned short* dst = kb + ((size_t)((b * NHK + khead) * LSEQ + l)) * HD;
    dst[d] = f2bf(x1 * cs.x - x2 * cs.y);
    dst[d + 32] = f2bf(x2 * cs.x + x1 * cs.y);
  } else if (bid < 4608) {
    // ---- V transpose -> vtb [B, HK, 80, L]; row 64 = ones
    const int vtid = bid - 4096;
    const int tt = vtid & 31, kh = (vtid >> 5) & 7, b = vtid >> 8;
    const unsigned short* src =
        qkvb + ((size_t)(b * LSEQ + tt * 64)) * QKV_N + DMODEL + 512 + kh * HD;
    {
      int row = tid >> 2, c0 = (tid & 3) * 16;
      *(uint4*)&Lt[row][c0] = *(const uint4*)(src + (size_t)row * QKV_N + c0);
      *(uint4*)&Lt[row][c0 + 8] = *(const uint4*)(src + (size_t)row * QKV_N + c0 + 8);
    }
    __syncthreads();
    {
      int d = tid >> 2, seg = tid & 3;
      unsigned short o[16];
#pragma unroll
      for (int k = 0; k < 16; ++k) o[k] = Lt[seg * 16 + k][d];
      unsigned short* dst =
          vtb + ((size_t)((b * NHK + kh) * 80 + d)) * LSEQ + tt * 64 + seg * 16;
      *(uint4*)dst = *(uint4*)o;
      *(uint4*)(dst + 8) = *(uint4*)(o + 8);
    }
    if (tid < 64)
      vtb[((size_t)((b * NHK + kh) * 80 + 64)) * LSEQ + tt * 64 + tid] = 0x3F80;  // 1.0
  } else {
    // ---- Wo -> bf16
    int i = (bid - 4608) * 256 + tid;
    float4 v = ((const float4*)Wo)[i];
    ushort4 o;
    o.x = f2bf(v.x); o.y = f2bf(v.y); o.z = f2bf(v.z); o.w = f2bf(v.w);
    ((ushort4*)wob)[i] = o;
  }
}

// ---------------------------------------------------------------------------
// attn8: flash MFMA causal GQA attention, single-barrier ping-pong staging.
// 3 blocks/CU (LDS 50 KB), grid (8=kh XCD pin, 64=band longest-first, 2=b)
// = 1024 variable-length blocks (band p has p/2+1 tiles), LPT order p=63-y.
// Block = 4 waves = 4 q-heads of one kv group sharing staged K/V tiles.
// S^T orientation; RoPE fused into Q load; P round-trips wave-private LDS
// ([32][64] + chunk-XOR involution, conflict-free); row-sums via ones-row
// of V^T (j=4 read row clamped into 72-row Vbuf).  Ping-pong unrolled by 2.
// Unchanged from r9 (in-session control).
// ---------------------------------------------------------------------------
__global__ __launch_bounds__(256, 3) void attn8(const unsigned short* __restrict__ qkvb,
                                                const float2* __restrict__ tab,
                                                const unsigned short* __restrict__ kb,
                                                const unsigned short* __restrict__ vtb,
                                                unsigned short* __restrict__ out) {
  const int kh = blockIdx.x;        // 0..7 fastest -> XCD pin
  const int p = 63 - blockIdx.y;    // band index, longest dispatched first
  const int b = blockIdx.z;
  const int wave = threadIdx.x >> 6, lane = threadIdx.x & 63;
  const int quad = lane >> 4, l16 = lane & 15;
  const int h = kh * 4 + wave;

  __shared__ unsigned short Kbuf[2][64 * 64];   // 16 KB ping-pong [key][d]
  __shared__ unsigned short Vbuf[2][72 * 64];   // 18 KB ping-pong [d][key]
  __shared__ unsigned short Ps_all[4][32][64];  // 16 KB wave-private P tiles
  unsigned short(*Ps)[64] = Ps_all[wave];

  const char* kbaseB = (const char*)(kb + ((size_t)(b * NHK + kh) * LSEQ) * HD);
  const char* vbaseB = (const char*)(vtb + ((size_t)(b * NHK + kh) * 80) * LSEQ);
  const float QSCALE = 0.125f * 1.44269504f;  // 1/sqrt(64) * log2(e)

  short8 qf[2][2];
  floatx4 O[2][5];

  auto loadQ = [&](int qb) {
#pragma unroll
    for (int i = 0; i < 2; ++i) {
      const int tok = qb + i * 16 + l16;
      const unsigned short* qr =
          qkvb + ((size_t)(b * LSEQ + tok)) * QKV_N + h * HD + quad * 8;
      uint4 lo = *(const uint4*)qr;         // d = quad*8 .. +7
      uint4 hi = *(const uint4*)(qr + 32);  // d+32
      const float2* tr = tab + (size_t)tok * 32 + quad * 8;
      float4 cs01 = ((const float4*)tr)[0];
      float4 cs23 = ((const float4*)tr)[1];
      float4 cs45 = ((const float4*)tr)[2];
      float4 cs67 = ((const float4*)tr)[3];
      float cosv[8] = {cs01.x, cs01.z, cs23.x, cs23.z, cs45.x, cs45.z, cs67.x, cs67.z};
      float sinv[8] = {cs01.y, cs01.w, cs23.y, cs23.w, cs45.y, cs45.w, cs67.y, cs67.w};
      const unsigned short* plo = (const unsigned short*)&lo;
      const unsigned short* phi = (const unsigned short*)&hi;
      unsigned short olo[8], ohi[8];
#pragma unroll
      for (int j = 0; j < 8; ++j) {
        float x1 = bf2f(plo[j]), x2 = bf2f(phi[j]);
        olo[j] = f2bf((x1 * cosv[j] - x2 * sinv[j]) * QSCALE);
        ohi[j] = f2bf((x2 * cosv[j] + x1 * sinv[j]) * QSCALE);
      }
      qf[i][0] = *(const short8*)olo;
      qf[i][1] = *(const short8*)ohi;
    }
  };
  auto zeroO = [&]() {
#pragma unroll
    for (int i = 0; i < 2; ++i)
#pragma unroll
      for (int j = 0; j < 5; ++j) O[i][j] = (floatx4){0.f, 0.f, 0.f, 0.f};
  };
  auto epilogue = [&](int qb) {
#pragma unroll
    for (int i = 0; i < 2; ++i) {
      float lv = __shfl(O[i][4][0], l16);  // lanes 0..15 hold l for q=16i+l16
      float inv = 1.0f / lv;
      const size_t obase =
          ((size_t)(b * LSEQ + qb + i * 16 + l16)) * DMODEL + h * HD;
#pragma unroll
      for (int j = 0; j < 4; ++j) {
        uint2 w;
        w.x = (unsigned)f2bf(O[i][j][0] * inv) | ((unsigned)f2bf(O[i][j][1] * inv) << 16);
        w.y = (unsigned)f2bf(O[i][j][2] * inv) | ((unsigned)f2bf(O[i][j][3] * inv) << 16);
        *(uint2*)&out[obase + j * 16 + quad * 4] = w;
      }
    }
  };
  auto stageKV = [&](int bi, int kt) {
    unsigned short* Kd = Kbuf[bi];
    unsigned short* Vd = Vbuf[bi];
#pragma unroll
    for (int c = wave; c < 17; c += 4) {
      if (c < 8) {
        int o = c * 1024 + lane * 16;
        int row = o >> 7;                    // key 0..63
        int lgc = ((o >> 4) & 7) ^ (row & 7);
        stage16g(kbaseB + (size_t)(kt * 64 + row) * 128 + lgc * 16,
                 Kd + c * 512, lane);
      } else {
        int o = (c - 8) * 1024 + lane * 16;
        int row = o >> 7;                    // d-row 0..71
        int lgc = ((o >> 4) & 7) ^ (row & 7);
        stage16g(vbaseB + (size_t)row * (LSEQ * 2) + (size_t)kt * 128 + lgc * 16,
                 Vd + (c - 8) * 512, lane);
      }
    }
  };

  const int qb = p * 32;
  const int last = p >> 1;   // final K-tile index
  const int N = last + 1;

  loadQ(qb);
  zeroO();
  stageKV(0, 0);

  // P store helper: logical cols [16t+quad*4, +4) of row 16i+l16, chunk-XOR
  // swizzled (chunk8 ^ (row&7)); 8B granule sits inside one 8-short chunk.
  auto storeP = [&](int i, int t, uint2 w) {
    int ph = (((2 * t + (quad >> 1)) ^ (l16 & 7)) << 3) + (quad & 1) * 4;
    *(uint2*)&Ps[16 * i + l16][ph] = w;
  };

  // one K/V-tile; cur/nxt become compile-time in the unrolled pairs
  auto body = [&](int m, int cur, int nxt) {
    __syncthreads();  // drains tile m's DMA (issued one compute-phase ago)

    if (m + 1 < N) stageKV(nxt, m + 1);

    const int kt = m;
    const unsigned short* Ks = Kbuf[cur];
    const unsigned short* Vs = Vbuf[cur];

    // ---- K frags from LDS (A-operand: m=key=16t+l16, k=d=32hf+quad*8+j) ----
    short8 kf[4][2];
#pragma unroll
    for (int t = 0; t < 4; ++t)
#pragma unroll
      for (int hf = 0; hf < 2; ++hf) {
        int row = t * 16 + l16;
        int phys = (4 * hf + quad) ^ (row & 7);
        kf[t][hf] = *(const short8*)&Ks[row * 64 + phys * 8];
      }

    // ---- S^T = K Q^T ----
    floatx4 st[4][2];
#pragma unroll
    for (int t = 0; t < 4; ++t)
#pragma unroll
      for (int i = 0; i < 2; ++i) {
        floatx4 z = {0.f, 0.f, 0.f, 0.f};
        z = __builtin_amdgcn_mfma_f32_16x16x32_bf16(kf[t][0], qf[i][0], z, 0, 0, 0);
        st[t][i] = __builtin_amdgcn_mfma_f32_16x16x32_bf16(kf[t][1], qf[i][1], z, 0, 0, 0);
      }

    // ---- P = exp2(S^T), causal mask only on the final kt (uniform branch) ----
    if (kt == last) {
      const int kofs = kt * 64 - qb;
#pragma unroll
      for (int t = 0; t < 4; ++t) {
        const int krow = kofs + 16 * t + quad * 4;
#pragma unroll
        for (int i = 0; i < 2; ++i) {
          const int qcol = 16 * i + l16;
          float sv[4];
#pragma unroll
          for (int r = 0; r < 4; ++r) {
            float v = st[t][i][r];
            if (krow + r > qcol) v = -1e30f;
            sv[r] = fast_exp2(v);
          }
          uint2 w;
          w.x = pack_bf_trunc(sv[1], sv[0]);
          w.y = pack_bf_trunc(sv[3], sv[2]);
          storeP(i, t, w);
        }
      }
    } else {
#pragma unroll
      for (int t = 0; t < 4; ++t)
#pragma unroll
        for (int i = 0; i < 2; ++i) {
          float sv[4];
#pragma unroll
          for (int r = 0; r < 4; ++r) sv[r] = fast_exp2(st[t][i][r]);
          uint2 w;
          w.x = pack_bf_trunc(sv[1], sv[0]);
          w.y = pack_bf_trunc(sv[3], sv[2]);
          storeP(i, t, w);
        }
    }

    // ---- O^T += V^T P^T ----
    short8 pf[2][2];
#pragma unroll
    for (int i = 0; i < 2; ++i)
#pragma unroll
      for (int hh = 0; hh < 2; ++hh)
        pf[i][hh] = *(const short8*)&Ps[16 * i + l16][((4 * hh + quad) ^ (l16 & 7)) << 3];
#pragma unroll
    for (int j = 0; j < 5; ++j) {
      int row = (j == 4) ? (64 + (l16 & 7)) : (j * 16 + l16);  // clamp into 72 rows
      short8 vf0 = *(const short8*)&Vs[row * 64 + ((quad ^ (row & 7)) * 8)];
      short8 vf1 = *(const short8*)&Vs[row * 64 + (((4 + quad) ^ (row & 7)) * 8)];
#pragma unroll
      for (int i = 0; i < 2; ++i) {
        O[i][j] = __builtin_amdgcn_mfma_f32_16x16x32_bf16(vf0, pf[i][0], O[i][j], 0, 0, 0);
        O[i][j] = __builtin_amdgcn_mfma_f32_16x16x32_bf16(vf1, pf[i][1], O[i][j], 0, 0, 0);
      }
    }
  };

#pragma unroll 1
  for (int m = 0; m + 1 < N; m += 2) {
    body(m, 0, 1);
    body(m + 1, 1, 0);
  }
  if (N & 1) body(N - 1, 0, 1);  // N odd -> N-1 even -> slot 0 (static)

  epilogue(qb);
}

extern "C" void kernel_launch(void* const* d_in, const int* in_sizes, int n_in,
                              void* d_out, int out_size, void* d_ws,
                              size_t ws_size, hipStream_t stream) {
  const float* x = (const float*)d_in[0];
  const float* Wq = (const float*)d_in[1];
  const float* Wk = (const float*)d_in[2];
  const float* Wv = (const float*)d_in[3];
  const float* Wo = (const float*)d_in[4];
  float* out = (float*)d_out;

  char* ws = (char*)d_ws;
  // layout (peak 64.5 MB):
  //   qkvb  bf16 [4096,3072] @ 0          25,165,824   gemm1..attn
  //   tab   f32  [2048,32,2] @ 25165824      524,288   prep..attn
  //   kb    bf16             @ 25690112    4,194,304   mid..attn
  //   vtb   bf16             @ 29884416    5,242,880   mid..attn
  //   xb    bf16 [4096,2048] @ 35127296   16,777,216   prep..gemm1 (dead after)
  //   wqkvb bf16 [3072,2048] @ 51904512   12,582,912   prep..gemm1 (dead after)
  //   aob = xb region (written by attn, xb dead)
  //   wob = wqkvb region (written by mid, after gemm1: wqkvb dead)
  unsigned short* qkvb = (unsigned short*)ws;
  float2* tab = (float2*)(ws + 25165824);
  unsigned short* kbuf = (unsigned short*)(ws + 25690112);
  unsigned short* vtb = (unsigned short*)(ws + 29884416);
  unsigned short* xb = (unsigned short*)(ws + 35127296);
  unsigned short* wqkvb = (unsigned short*)(ws + 51904512);
  unsigned short* aob = xb;
  unsigned short* wob = wqkvb;

  const int M = NB * LSEQ;  // 4096
  dim3 blk(256);

  // fused prep: rope table + x->bf16 + Wqkv->bf16 (segments block-aligned)
  prep<<<14592, blk, 0, stream>>>(x, Wq, Wk, Wv, tab, xb, wqkvb);

  // QKV projection -> bf16 qkvb (128x128 tiles, 8 waves: 24x32 = 768 blocks
  // = 3/CU = 24 waves/CU, XCD-swizzled)
  gemm8w<true><<<dim3(QKV_N / 128, M / 128), dim3(512), 0, stream>>>(
      xb, wqkvb, qkvb, DMODEL, QKV_N);

  // fused mid: ropek + vt + Wo->bf16
  mid<<<8704, blk, 0, stream>>>(qkvb, tab, Wo, kbuf, vtb, wob);

  // 1024 variable-length blocks, longest-first, 3 blocks/CU
  attn8<<<dim3(NHK, 64, NB), blk, 0, stream>>>(qkvb, tab, kbuf, vtb, aob);

  // output projection -> fp32 out (128x128 tiles, 8 waves: 16x32 = 512
  // blocks = 2/CU = 16 waves/CU, XCD-swizzled)
  gemm8w<false><<<dim3(DMODEL / 128, M / 128), dim3(512), 0, stream>>>(
      aob, wob, out, DMODEL, DMODEL);
}

// Round 11
// 285.313 us; speedup vs baseline: 1.0155x; 1.0155x over previous
//
#include <hip/hip_runtime.h>
#include <math.h>

#define NH 32
#define NHK 8
#define HD 64
#define DMODEL 2048
#define LSEQ 2048
#define NB 2
#define QKV_N 3072   // 2048 q + 512 k + 512 v

typedef __attribute__((ext_vector_type(8))) short short8;
typedef __attribute__((ext_vector_type(4))) float floatx4;

__device__ __forceinline__ unsigned short f2bf(float f) {
  unsigned u = __float_as_uint(f);
  return (unsigned short)((u + 0x7FFFu + ((u >> 16) & 1u)) >> 16);  // RNE
}
__device__ __forceinline__ float bf2f(unsigned short v) {
  return __uint_as_float((unsigned)v << 16);
}
__device__ __forceinline__ float fast_exp2(float x) {
#if __has_builtin(__builtin_amdgcn_exp2f)
  return __builtin_amdgcn_exp2f(x);
#else
  return __expf(x * 0.69314718f);
#endif
}
// pack bf16(hi),bf16(lo) from two fp32 by truncation: 1 v_perm_b32
__device__ __forceinline__ unsigned pack_bf_trunc(float hi, float lo) {
  return __builtin_amdgcn_perm(__float_as_uint(hi), __float_as_uint(lo), 0x07060302u);
}
// async 16B global->LDS, per-lane global address; lds base must be
// wave-uniform, lanes land at base+lane*16
__device__ __forceinline__ void stage16g(const char* g_lane,
                                         unsigned short* lds_wave_base, int lane) {
#if __has_builtin(__builtin_amdgcn_global_load_lds)
  __builtin_amdgcn_global_load_lds(
      (const __attribute__((address_space(1))) void*)(g_lane),
      (__attribute__((address_space(3))) void*)(lds_wave_base), 16, 0, 0);
#else
  *(uint4*)(lds_wave_base + lane * 8) = *(const uint4*)g_lane;
#endif
}

// ---------------------------------------------------------------------------
// prep: fused {rope_tab | x->bf16 | Wq|Wk|Wv->bf16}.  All segment boundaries
// are 256-block-aligned -> no intra-block divergence.
// ---------------------------------------------------------------------------
__global__ __launch_bounds__(256) void prep(const float* __restrict__ x,
                                            const float* __restrict__ Wq,
                                            const float* __restrict__ Wk,
                                            const float* __restrict__ Wv,
                                            float2* __restrict__ tab,
                                            unsigned short* __restrict__ xb,
                                            unsigned short* __restrict__ wqkvb) {
  const int NTAB = LSEQ * 32;                    // 65536
  const int NX = NB * LSEQ * DMODEL / 4;         // 2097152
  int idx = blockIdx.x * 256 + threadIdx.x;
  if (idx < NTAB) {
    int d = idx & 31, l = idx >> 5;
    float invf = (float)pow(10000.0, -(double)d / 32.0);
    float ang = (float)l * invf;
    double sd, cd;
    sincos((double)ang, &sd, &cd);
    tab[idx] = make_float2((float)cd, (float)sd);
    return;
  }
  idx -= NTAB;
  if (idx < NX) {
    float4 v = ((const float4*)x)[idx];
    ushort4 o;
    o.x = f2bf(v.x); o.y = f2bf(v.y); o.z = f2bf(v.z); o.w = f2bf(v.w);
    ((ushort4*)xb)[idx] = o;
    return;
  }
  idx -= NX;
  const int NQ = DMODEL * DMODEL / 4, NK = 512 * DMODEL / 4;
  const float* src;
  int off;
  if (idx < NQ) { src = Wq; off = idx; }
  else if (idx < NQ + NK) { src = Wk; off = idx - NQ; }
  else { src = Wv; off = idx - NQ - NK; }
  float4 v = ((const float4*)src)[off];
  ushort4 o;
  o.x = f2bf(v.x); o.y = f2bf(v.y); o.z = f2bf(v.z); o.w = f2bf(v.w);
  ((ushort4*)wqkvb)[idx] = o;
}

// ---------------------------------------------------------------------------
// gemm4: bf16 NT GEMM, 128x128 tile, BK=32, 4 waves (2Mx2N), 3 LDS K-tile
// slots (48 KB -> 3 blocks/CU), 2-tiles-ahead async staging with COUNTED
// vmcnt (steady vmcnt(4), never 0 until the last tile), one raw s_barrier
// per K-tile, setprio around MFMA clusters, T1 XCD swizzle, unroll-by-3
// static LDS slots.
//
// STATUS (final): best-measured GEMM structure for this problem.  Ledger:
// three distinct schedules (256^2/1blk/deep-vmcnt r2, 128^2/4w/3blk r6-r9,
// 128^2/8w r10) all land 64-70 us/projection; r10's 8-wave variant REGRESSED
// (dur +5%, FETCH +60% from degraded L2 line reuse of 16-row staging) and is
// reverted here.  Counter-confirmed nulls: phase grafts (r3,r5), VALU
// strength-reduction (r7), Ps conflict fix (r9).  Limiter = per-tile latency
// floor of the barrier-per-K-step family (no saturated pipe: MFMA ~32%,
// VALU 15%, LDS ~60%, HBM 17%).
// ---------------------------------------------------------------------------
template <bool BF16C>
__global__ __launch_bounds__(256, 3) void gemm4(const unsigned short* __restrict__ A,
                                                const unsigned short* __restrict__ B,
                                                void* __restrict__ Cv, int K, int ldc) {
  __shared__ unsigned short As[3 * 128 * 32];  // 24 KB
  __shared__ unsigned short Bs[3 * 128 * 32];  // 24 KB

  const int tid = threadIdx.x;
  const int wave = tid >> 6, lane = tid & 63;
  const int quad = lane >> 4, l16 = lane & 15;
  const int wm = wave & 1, wn = wave >> 1;  // 2 x 2 wave grid

  // --- XCD-chunked bijective block swizzle (nwg % 8 == 0: 768 and 512)
  const int nwg = gridDim.x * gridDim.y;
  const int orig = blockIdx.y * gridDim.x + blockIdx.x;
  const int swz = (orig & 7) * (nwg >> 3) + (orig >> 3);
  const int bx = swz % gridDim.x, by = swz / gridDim.x;
  const int m0 = by * 128, n0 = bx * 128;

  const int kt = K >> 5;  // number of BK=32 K-tiles

  // staging source (per-lane): row = wave*16 + lane>>2 (u adds 64),
  // chunk = (lane&3)^((lane>>3)&3)  [pre-swizzled for the sw8 read]
  const int sgrow = wave * 16 + (lane >> 2);
  const int cchunk = (lane & 3) ^ ((lane >> 3) & 3);
  const char* AgB = (const char*)(A + (size_t)(m0 + sgrow) * K + cchunk * 8);
  const char* BgB = (const char*)(B + (size_t)(n0 + sgrow) * K + cchunk * 8);

  auto stageA = [&](int slot, int t2) {
    unsigned short* dst = &As[slot * 4096 + wave * 512];
#pragma unroll
    for (int u = 0; u < 2; ++u)
      stage16g(AgB + ((size_t)u * 64 * K + (size_t)t2 * 32) * 2, dst + u * 2048, lane);
  };
  auto stageB = [&](int slot, int t2) {
    unsigned short* dst = &Bs[slot * 4096 + wave * 512];
#pragma unroll
    for (int u = 0; u < 2; ++u)
      stage16g(BgB + ((size_t)u * 64 * K + (size_t)t2 * 32) * 2, dst + u * 2048, lane);
  };

  // read swizzle: chunk quad of row r sits at position quad^((r>>1)&3)
  const int sw8 = (quad ^ ((l16 >> 1) & 3)) * 8;

  floatx4 acc[4][4] = {};

  // prologue: stage tiles 0,1 (2 tiles = 8 loads/wave in flight)
  stageA(0, 0); stageB(0, 0);
  stageA(1, 1); stageB(1, 1);

  // tile body; sl/sl2 become compile-time constants in the unrolled groups
  auto tile = [&](int t, int sl, int sl2) {
    if (t + 1 < kt) asm volatile("s_waitcnt vmcnt(4)" ::: "memory");
    else            asm volatile("s_waitcnt vmcnt(0)" ::: "memory");
    __builtin_amdgcn_s_barrier();
    __builtin_amdgcn_sched_barrier(0);

    const unsigned short* Arow = &As[sl * 4096] + (wm * 64 + l16) * 32 + sw8;
    const unsigned short* Brow = &Bs[sl * 4096] + (wn * 64 + l16) * 32 + sw8;

    short8 bfr[4], af[4];
#pragma unroll
    for (int j = 0; j < 4; ++j) bfr[j] = *(const short8*)(Brow + j * 16 * 32);
#pragma unroll
    for (int i = 0; i < 4; ++i) af[i] = *(const short8*)(Arow + i * 16 * 32);

    if (t + 2 < kt) stageA(sl2, t + 2);

    __builtin_amdgcn_s_setprio(1);
#pragma unroll
    for (int i = 0; i < 2; ++i)
#pragma unroll
      for (int j = 0; j < 4; ++j)
        acc[i][j] = __builtin_amdgcn_mfma_f32_16x16x32_bf16(af[i], bfr[j], acc[i][j], 0, 0, 0);
    __builtin_amdgcn_s_setprio(0);

    if (t + 2 < kt) stageB(sl2, t + 2);

    __builtin_amdgcn_s_setprio(1);
#pragma unroll
    for (int i = 2; i < 4; ++i)
#pragma unroll
      for (int j = 0; j < 4; ++j)
        acc[i][j] = __builtin_amdgcn_mfma_f32_16x16x32_bf16(af[i], bfr[j], acc[i][j], 0, 0, 0);
    __builtin_amdgcn_s_setprio(0);
  };

#pragma unroll 1
  for (int g = 0; g < kt / 3; ++g) {
#pragma unroll
    for (int u3 = 0; u3 < 3; ++u3)
      tile(g * 3 + u3, u3, (u3 + 2) % 3);   // static slots after unroll
  }
#pragma unroll 1
  for (int t = (kt / 3) * 3; t < kt; ++t)
    tile(t, t % 3, (t + 2) % 3);            // <=2 tail tiles, runtime slot

#pragma unroll
  for (int i = 0; i < 4; ++i)
#pragma unroll
    for (int j = 0; j < 4; ++j)
#pragma unroll
      for (int r = 0; r < 4; ++r) {
        size_t idx = (size_t)(m0 + wm * 64 + i * 16 + quad * 4 + r) * ldc +
                     n0 + wn * 64 + j * 16 + l16;
        if (BF16C)
          ((unsigned short*)Cv)[idx] = f2bf(acc[i][j][r]);
        else
          ((float*)Cv)[idx] = acc[i][j][r];
      }
}

// ---------------------------------------------------------------------------
// mid: fused {RoPE-k | V-transpose | Wo->bf16}, all consumers of post-gemm1
// state.  Block-aligned segments:
//   blocks [0,4096):    ropek  (1,048,576 threads)
//   blocks [4096,4608): vt     (512 shaped blocks, uses LDS+syncthreads)
//   blocks [4608,8704): cvt Wo (1,048,576 threads; wqkvb dead -> wob reuse ok)
// ---------------------------------------------------------------------------
__global__ __launch_bounds__(256) void mid(const unsigned short* __restrict__ qkvb,
                                           const float2* __restrict__ tab,
                                           const float* __restrict__ Wo,
                                           unsigned short* __restrict__ kb,
                                           unsigned short* __restrict__ vtb,
                                           unsigned short* __restrict__ wob) {
  __shared__ unsigned short Lt[64][72];
  const int bid = blockIdx.x, tid = threadIdx.x;
  if (bid < 4096) {
    // ---- RoPE k -> kb [B, HK, L, 64]
    int t = bid * 256 + tid;
    int d = t & 31;
    int rest = t >> 5;
    int khead = rest & 7;
    int bl = rest >> 3;
    int l = bl & (LSEQ - 1);
    int b = bl >> 11;
    const unsigned short* src = qkvb + (size_t)bl * QKV_N + DMODEL + khead * HD;
    float2 cs = tab[(size_t)l * 32 + d];
    float x1 = bf2f(src[d]), x2 = bf2f(src[d + 32]);
    unsigned short* dst = kb + ((size_t)((b * NHK + khead) * LSEQ + l)) * HD;
    dst[d] = f2bf(x1 * cs.x - x2 * cs.y);
    dst[d + 32] = f2bf(x2 * cs.x + x1 * cs.y);
  } else if (bid < 4608) {
    // ---- V transpose -> vtb [B, HK, 80, L]; row 64 = ones
    const int vtid = bid - 4096;
    const int tt = vtid & 31, kh = (vtid >> 5) & 7, b = vtid >> 8;
    const unsigned short* src =
        qkvb + ((size_t)(b * LSEQ + tt * 64)) * QKV_N + DMODEL + 512 + kh * HD;
    {
      int row = tid >> 2, c0 = (tid & 3) * 16;
      *(uint4*)&Lt[row][c0] = *(const uint4*)(src + (size_t)row * QKV_N + c0);
      *(uint4*)&Lt[row][c0 + 8] = *(const uint4*)(src + (size_t)row * QKV_N + c0 + 8);
    }
    __syncthreads();
    {
      int d = tid >> 2, seg = tid & 3;
      unsigned short o[16];
#pragma unroll
      for (int k = 0; k < 16; ++k) o[k] = Lt[seg * 16 + k][d];
      unsigned short* dst =
          vtb + ((size_t)((b * NHK + kh) * 80 + d)) * LSEQ + tt * 64 + seg * 16;
      *(uint4*)dst = *(uint4*)o;
      *(uint4*)(dst + 8) = *(uint4*)(o + 8);
    }
    if (tid < 64)
      vtb[((size_t)((b * NHK + kh) * 80 + 64)) * LSEQ + tt * 64 + tid] = 0x3F80;  // 1.0
  } else {
    // ---- Wo -> bf16
    int i = (bid - 4608) * 256 + tid;
    float4 v = ((const float4*)Wo)[i];
    ushort4 o;
    o.x = f2bf(v.x); o.y = f2bf(v.y); o.z = f2bf(v.z); o.w = f2bf(v.w);
    ((ushort4*)wob)[i] = o;
  }
}

// ---------------------------------------------------------------------------
// attn8: flash MFMA causal GQA attention, single-barrier ping-pong staging.
// 3 blocks/CU (LDS 50 KB), grid (8=kh XCD pin, 64=band longest-first, 2=b)
// = 1024 variable-length blocks (band p has p/2+1 tiles), LPT order p=63-y.
// Block = 4 waves = 4 q-heads of one kv group sharing staged K/V tiles.
// S^T orientation; RoPE fused into Q load; P round-trips wave-private LDS
// ([32][64] + chunk-XOR involution, conflict-free); row-sums via ones-row
// of V^T (j=4 read row clamped into 72-row Vbuf).  Ping-pong unrolled by 2.
// ---------------------------------------------------------------------------
__global__ __launch_bounds__(256, 3) void attn8(const unsigned short* __restrict__ qkvb,
                                                const float2* __restrict__ tab,
                                                const unsigned short* __restrict__ kb,
                                                const unsigned short* __restrict__ vtb,
                                                unsigned short* __restrict__ out) {
  const int kh = blockIdx.x;        // 0..7 fastest -> XCD pin
  const int p = 63 - blockIdx.y;    // band index, longest dispatched first
  const int b = blockIdx.z;
  const int wave = threadIdx.x >> 6, lane = threadIdx.x & 63;
  const int quad = lane >> 4, l16 = lane & 15;
  const int h = kh * 4 + wave;

  __shared__ unsigned short Kbuf[2][64 * 64];   // 16 KB ping-pong [key][d]
  __shared__ unsigned short Vbuf[2][72 * 64];   // 18 KB ping-pong [d][key]
  __shared__ unsigned short Ps_all[4][32][64];  // 16 KB wave-private P tiles
  unsigned short(*Ps)[64] = Ps_all[wave];

  const char* kbaseB = (const char*)(kb + ((size_t)(b * NHK + kh) * LSEQ) * HD);
  const char* vbaseB = (const char*)(vtb + ((size_t)(b * NHK + kh) * 80) * LSEQ);
  const float QSCALE = 0.125f * 1.44269504f;  // 1/sqrt(64) * log2(e)

  short8 qf[2][2];
  floatx4 O[2][5];

  auto loadQ = [&](int qb) {
#pragma unroll
    for (int i = 0; i < 2; ++i) {
      const int tok = qb + i * 16 + l16;
      const unsigned short* qr =
          qkvb + ((size_t)(b * LSEQ + tok)) * QKV_N + h * HD + quad * 8;
      uint4 lo = *(const uint4*)qr;         // d = quad*8 .. +7
      uint4 hi = *(const uint4*)(qr + 32);  // d+32
      const float2* tr = tab + (size_t)tok * 32 + quad * 8;
      float4 cs01 = ((const float4*)tr)[0];
      float4 cs23 = ((const float4*)tr)[1];
      float4 cs45 = ((const float4*)tr)[2];
      float4 cs67 = ((const float4*)tr)[3];
      float cosv[8] = {cs01.x, cs01.z, cs23.x, cs23.z, cs45.x, cs45.z, cs67.x, cs67.z};
      float sinv[8] = {cs01.y, cs01.w, cs23.y, cs23.w, cs45.y, cs45.w, cs67.y, cs67.w};
      const unsigned short* plo = (const unsigned short*)&lo;
      const unsigned short* phi = (const unsigned short*)&hi;
      unsigned short olo[8], ohi[8];
#pragma unroll
      for (int j = 0; j < 8; ++j) {
        float x1 = bf2f(plo[j]), x2 = bf2f(phi[j]);
        olo[j] = f2bf((x1 * cosv[j] - x2 * sinv[j]) * QSCALE);
        ohi[j] = f2bf((x2 * cosv[j] + x1 * sinv[j]) * QSCALE);
      }
      qf[i][0] = *(const short8*)olo;
      qf[i][1] = *(const short8*)ohi;
    }
  };
  auto zeroO = [&]() {
#pragma unroll
    for (int i = 0; i < 2; ++i)
#pragma unroll
      for (int j = 0; j < 5; ++j) O[i][j] = (floatx4){0.f, 0.f, 0.f, 0.f};
  };
  auto epilogue = [&](int qb) {
#pragma unroll
    for (int i = 0; i < 2; ++i) {
      float lv = __shfl(O[i][4][0], l16);  // lanes 0..15 hold l for q=16i+l16
      float inv = 1.0f / lv;
      const size_t obase =
          ((size_t)(b * LSEQ + qb + i * 16 + l16)) * DMODEL + h * HD;
#pragma unroll
      for (int j = 0; j < 4; ++j) {
        uint2 w;
        w.x = (unsigned)f2bf(O[i][j][0] * inv) | ((unsigned)f2bf(O[i][j][1] * inv) << 16);
        w.y = (unsigned)f2bf(O[i][j][2] * inv) | ((unsigned)f2bf(O[i][j][3] * inv) << 16);
        *(uint2*)&out[obase + j * 16 + quad * 4] = w;
      }
    }
  };
  auto stageKV = [&](int bi, int kt) {
    unsigned short* Kd = Kbuf[bi];
    unsigned short* Vd = Vbuf[bi];
#pragma unroll
    for (int c = wave; c < 17; c += 4) {
      if (c < 8) {
        int o = c * 1024 + lane * 16;
        int row = o >> 7;                    // key 0..63
        int lgc = ((o >> 4) & 7) ^ (row & 7);
        stage16g(kbaseB + (size_t)(kt * 64 + row) * 128 + lgc * 16,
                 Kd + c * 512, lane);
      } else {
        int o = (c - 8) * 1024 + lane * 16;
        int row = o >> 7;                    // d-row 0..71
        int lgc = ((o >> 4) & 7) ^ (row & 7);
        stage16g(vbaseB + (size_t)row * (LSEQ * 2) + (size_t)kt * 128 + lgc * 16,
                 Vd + (c - 8) * 512, lane);
      }
    }
  };

  const int qb = p * 32;
  const int last = p >> 1;   // final K-tile index
  const int N = last + 1;

  loadQ(qb);
  zeroO();
  stageKV(0, 0);

  // P store helper: logical cols [16t+quad*4, +4) of row 16i+l16, chunk-XOR
  // swizzled (chunk8 ^ (row&7)); 8B granule sits inside one 8-short chunk.
  auto storeP = [&](int i, int t, uint2 w) {
    int ph = (((2 * t + (quad >> 1)) ^ (l16 & 7)) << 3) + (quad & 1) * 4;
    *(uint2*)&Ps[16 * i + l16][ph] = w;
  };

  // one K/V-tile; cur/nxt become compile-time in the unrolled pairs
  auto body = [&](int m, int cur, int nxt) {
    __syncthreads();  // drains tile m's DMA (issued one compute-phase ago)

    if (m + 1 < N) stageKV(nxt, m + 1);

    const int kt = m;
    const unsigned short* Ks = Kbuf[cur];
    const unsigned short* Vs = Vbuf[cur];

    // ---- K frags from LDS (A-operand: m=key=16t+l16, k=d=32hf+quad*8+j) ----
    short8 kf[4][2];
#pragma unroll
    for (int t = 0; t < 4; ++t)
#pragma unroll
      for (int hf = 0; hf < 2; ++hf) {
        int row = t * 16 + l16;
        int phys = (4 * hf + quad) ^ (row & 7);
        kf[t][hf] = *(const short8*)&Ks[row * 64 + phys * 8];
      }

    // ---- S^T = K Q^T ----
    floatx4 st[4][2];
#pragma unroll
    for (int t = 0; t < 4; ++t)
#pragma unroll
      for (int i = 0; i < 2; ++i) {
        floatx4 z = {0.f, 0.f, 0.f, 0.f};
        z = __builtin_amdgcn_mfma_f32_16x16x32_bf16(kf[t][0], qf[i][0], z, 0, 0, 0);
        st[t][i] = __builtin_amdgcn_mfma_f32_16x16x32_bf16(kf[t][1], qf[i][1], z, 0, 0, 0);
      }

    // ---- P = exp2(S^T), causal mask only on the final kt (uniform branch) ----
    if (kt == last) {
      const int kofs = kt * 64 - qb;
#pragma unroll
      for (int t = 0; t < 4; ++t) {
        const int krow = kofs + 16 * t + quad * 4;
#pragma unroll
        for (int i = 0; i < 2; ++i) {
          const int qcol = 16 * i + l16;
          float sv[4];
#pragma unroll
          for (int r = 0; r < 4; ++r) {
            float v = st[t][i][r];
            if (krow + r > qcol) v = -1e30f;
            sv[r] = fast_exp2(v);
          }
          uint2 w;
          w.x = pack_bf_trunc(sv[1], sv[0]);
          w.y = pack_bf_trunc(sv[3], sv[2]);
          storeP(i, t, w);
        }
      }
    } else {
#pragma unroll
      for (int t = 0; t < 4; ++t)
#pragma unroll
        for (int i = 0; i < 2; ++i) {
          float sv[4];
#pragma unroll
          for (int r = 0; r < 4; ++r) sv[r] = fast_exp2(st[t][i][r]);
          uint2 w;
          w.x = pack_bf_trunc(sv[1], sv[0]);
          w.y = pack_bf_trunc(sv[3], sv[2]);
          storeP(i, t, w);
        }
    }

    // ---- O^T += V^T P^T ----
    short8 pf[2][2];
#pragma unroll
    for (int i = 0; i < 2; ++i)
#pragma unroll
      for (int hh = 0; hh < 2; ++hh)
        pf[i][hh] = *(const short8*)&Ps[16 * i + l16][((4 * hh + quad) ^ (l16 & 7)) << 3];
#pragma unroll
    for (int j = 0; j < 5; ++j) {
      int row = (j == 4) ? (64 + (l16 & 7)) : (j * 16 + l16);  // clamp into 72 rows
      short8 vf0 = *(const short8*)&Vs[row * 64 + ((quad ^ (row & 7)) * 8)];
      short8 vf1 = *(const short8*)&Vs[row * 64 + (((4 + quad) ^ (row & 7)) * 8)];
#pragma unroll
      for (int i = 0; i < 2; ++i) {
        O[i][j] = __builtin_amdgcn_mfma_f32_16x16x32_bf16(vf0, pf[i][0], O[i][j], 0, 0, 0);
        O[i][j] = __builtin_amdgcn_mfma_f32_16x16x32_bf16(vf1, pf[i][1], O[i][j], 0, 0, 0);
      }
    }
  };

#pragma unroll 1
  for (int m = 0; m + 1 < N; m += 2) {
    body(m, 0, 1);
    body(m + 1, 1, 0);
  }
  if (N & 1) body(N - 1, 0, 1);  // N odd -> N-1 even -> slot 0 (static)

  epilogue(qb);
}

extern "C" void kernel_launch(void* const* d_in, const int* in_sizes, int n_in,
                              void* d_out, int out_size, void* d_ws,
                              size_t ws_size, hipStream_t stream) {
  const float* x = (const float*)d_in[0];
  const float* Wq = (const float*)d_in[1];
  const float* Wk = (const float*)d_in[2];
  const float* Wv = (const float*)d_in[3];
  const float* Wo = (const float*)d_in[4];
  float* out = (float*)d_out;

  char* ws = (char*)d_ws;
  // layout (peak 64.5 MB):
  //   qkvb  bf16 [4096,3072] @ 0          25,165,824   gemm1..attn
  //   tab   f32  [2048,32,2] @ 25165824      524,288   prep..attn
  //   kb    bf16             @ 25690112    4,194,304   mid..attn
  //   vtb   bf16             @ 29884416    5,242,880   mid..attn
  //   xb    bf16 [4096,2048] @ 35127296   16,777,216   prep..gemm1 (dead after)
  //   wqkvb bf16 [3072,2048] @ 51904512   12,582,912   prep..gemm1 (dead after)
  //   aob = xb region (written by attn, xb dead)
  //   wob = wqkvb region (written by mid, after gemm1: wqkvb dead)
  unsigned short* qkvb = (unsigned short*)ws;
  float2* tab = (float2*)(ws + 25165824);
  unsigned short* kbuf = (unsigned short*)(ws + 25690112);
  unsigned short* vtb = (unsigned short*)(ws + 29884416);
  unsigned short* xb = (unsigned short*)(ws + 35127296);
  unsigned short* wqkvb = (unsigned short*)(ws + 51904512);
  unsigned short* aob = xb;
  unsigned short* wob = wqkvb;

  const int M = NB * LSEQ;  // 4096
  dim3 blk(256);

  // fused prep: rope table + x->bf16 + Wqkv->bf16 (segments block-aligned)
  prep<<<14592, blk, 0, stream>>>(x, Wq, Wk, Wv, tab, xb, wqkvb);

  // QKV projection -> bf16 qkvb (128x128 tiles: 24x32 = 768 blocks = 3/CU,
  // XCD-swizzled)
  gemm4<true><<<dim3(QKV_N / 128, M / 128), blk, 0, stream>>>(
      xb, wqkvb, qkvb, DMODEL, QKV_N);

  // fused mid: ropek + vt + Wo->bf16
  mid<<<8704, blk, 0, stream>>>(qkvb, tab, Wo, kbuf, vtb, wob);

  // 1024 variable-length blocks, longest-first, 3 blocks/CU
  attn8<<<dim3(NHK, 64, NB), blk, 0, stream>>>(qkvb, tab, kbuf, vtb, aob);

  // output projection -> fp32 out (128x128 tiles: 16x32 = 512 blocks = 2/CU,
  // XCD-swizzled)
  gemm4<false><<<dim3(DMODEL / 128, M / 128), blk, 0, stream>>>(
      aob, wob, out, DMODEL, DMODEL);
}